// Round 1
// baseline (779.906 us; speedup 1.0000x reference)
//
#include <hip/hip_runtime.h>

#define N 50000
#define E 800000
#define H 128
#define G 64
#define OUTC 10
#define L 6
#define EPS 1e-5f
#define SLOTS 64   // fixed bucket capacity; deg ~ Poisson(16), P(deg>64) ~ 2e-18

typedef unsigned short ushort_t;
typedef __attribute__((ext_vector_type(8))) short short8;
typedef __attribute__((ext_vector_type(8))) unsigned short ushort8;
typedef __attribute__((ext_vector_type(4))) float floatx4;

__device__ __forceinline__ void atomAddF(float* p, float v) {
  unsafeAtomicAdd(p, v);   // hw global_atomic_add_f32 on gfx950
}

__device__ __forceinline__ unsigned short f2bf(float f) {
  unsigned u = __float_as_uint(f);
  unsigned r = (u + 0x7FFF + ((u >> 16) & 1)) >> 16;  // RNE
  return (unsigned short)r;
}
__device__ __forceinline__ float bf2f(unsigned short b) {
  return __uint_as_float(((unsigned)b) << 16);
}

// ---------------- init ----------------
__global__ void zero_kernel(int* __restrict__ p, int n) {
  int i = blockIdx.x * blockDim.x + threadIdx.x;
  if (i < n) p[i] = 0;
}

// one-pass bucket CSR build: pos = atomicAdd(cnt[d]); csr[d*64+pos] = src
// replaces deg_count + 3-phase scan + rowptr-indexed fill
__global__ void csr_fill_kernel(const int* __restrict__ src, const int* __restrict__ dst,
                                int* __restrict__ cnt, int* __restrict__ csr) {
  int e = blockIdx.x * blockDim.x + threadIdx.x;
  if (e < E) {
    int d = dst[e];
    int pos = atomicAdd(&cnt[d], 1);
    if (pos < SLOTS) csr[(d << 6) + pos] = src[e];
  }
}

__global__ void dinv_kernel(const int* __restrict__ cnt, float* __restrict__ dinv) {
  int n = blockIdx.x * blockDim.x + threadIdx.x;
  if (n < N) dinv[n] = rsqrtf((float)(cnt[n] + 1));
}

// prep: conv_W -> bf16 transposed WT[l][n][k] (196 KB total)
__global__ void prep_kernel(const float* __restrict__ convW, ushort_t* __restrict__ WT) {
  int j = blockIdx.x * 256 + threadIdx.x;
  if (j < L * H * H) {
    int l = j >> 14, r = j & 16383;   // H*H = 16384
    int n = r >> 7, k = r & 127;
    WT[j] = f2bf(convW[l * 16384 + k * 128 + n]);
  }
}

__global__ void cnt_kernel(const int* __restrict__ batch, float* __restrict__ cntg) {
  __shared__ int lb[G + 1];
  int t = threadIdx.x;  // 128 threads
  if (t <= G) {
    int lo = 0, hi = N;
    while (lo < hi) { int m = (lo + hi) >> 1; if (batch[m] < t) lo = m + 1; else hi = m; }
    lb[t] = lo;
  }
  __syncthreads();
  if (t < G) cntg[t] = (float)(lb[t + 1] - lb[t]);
}

// ---------------- MFMA GEMM: hWs[row] = dinv[row] * (f(A)@W)[row], bf16 ----------------
// A source: Af (f32, layer 0) or Ab (bf16, layers 1..5).
// f = identity (layer 0) or BN+ReLU applied in-register on A fragments.
// LDS-free: A frags from global (L2/L3-resident), B frags from WT (L1-resident).
// block: 256 thr = 4 waves; block tile 64 rows; wave tile 16 rows x 128 cols.
// A layout: A[m=lane&15][k=quad*8+j]; C/D: col=lane&15, row=quad*4+reg.
__global__ __launch_bounds__(256) void gemm_mfma_kernel(
    const ushort_t* __restrict__ Ab, const float* __restrict__ Af,
    const ushort_t* __restrict__ WT,
    const float* __restrict__ dinv, ushort_t* __restrict__ hWs,
    const float* __restrict__ bnsums, const float* __restrict__ gamma,
    const float* __restrict__ beta)
{
  const int tid = threadIdx.x;
  const int wave = tid >> 6, lane = tid & 63;
  const int quad = lane >> 4, m = lane & 15;
  const int row0 = blockIdx.x * 64 + wave * 16;
  const int arow = min(row0 + m, N - 1);
  const float invN = 1.0f / (float)N;

  short8 afrag[4];
  if (Af) {
    // layer 0: read f32 x directly, convert RNE in-register
#pragma unroll
    for (int kc = 0; kc < 4; ++kc) {
      const float* p = &Af[arow * H + kc * 32 + quad * 8];
      float4 f0 = *(const float4*)p;
      float4 f1 = *(const float4*)(p + 4);
      short8 a;
      a[0] = (short)f2bf(f0.x); a[1] = (short)f2bf(f0.y);
      a[2] = (short)f2bf(f0.z); a[3] = (short)f2bf(f0.w);
      a[4] = (short)f2bf(f1.x); a[5] = (short)f2bf(f1.y);
      a[6] = (short)f2bf(f1.z); a[7] = (short)f2bf(f1.w);
      afrag[kc] = a;
    }
  } else {
#pragma unroll
    for (int kc = 0; kc < 4; ++kc) {
      ushort8 raw = *(const ushort8*)&Ab[arow * H + kc * 32 + quad * 8];
      if (bnsums) {
        const int k0 = kc * 32 + quad * 8;
#pragma unroll
        for (int j = 0; j < 8; ++j) {
          float s = bnsums[k0 + j], q = bnsums[128 + k0 + j];
          float mu = s * invN;
          float var = q * invN - mu * mu;
          float rs = rsqrtf(var + EPS);
          float sc = gamma[k0 + j] * rs;
          float sh = beta[k0 + j] - mu * sc;
          raw[j] = f2bf(fmaxf(bf2f(raw[j]) * sc + sh, 0.f));
        }
      }
      short8 a;
#pragma unroll
      for (int j = 0; j < 8; ++j) a[j] = (short)raw[j];
      afrag[kc] = a;
    }
  }

  float dv[4];
#pragma unroll
  for (int i = 0; i < 4; ++i) {
    int r = row0 + quad * 4 + i;
    dv[i] = (r < N) ? dinv[r] : 0.f;
  }

  const short* WTs = (const short*)WT;
#pragma unroll
  for (int nt = 0; nt < 8; ++nt) {
    floatx4 acc = {0.f, 0.f, 0.f, 0.f};
#pragma unroll
    for (int kc = 0; kc < 4; ++kc) {
      short8 bfrag = *(const short8*)&WTs[(nt * 16 + m) * H + kc * 32 + quad * 8];
      acc = __builtin_amdgcn_mfma_f32_16x16x32_bf16(afrag[kc], bfrag, acc, 0, 0, 0);
    }
    int col = nt * 16 + m;
#pragma unroll
    for (int i = 0; i < 4; ++i) {
      int r = row0 + quad * 4 + i;
      if (r < N) hWs[r * H + col] = f2bf(acc[i] * dv[i]);
    }
  }
}

// ---------------- CSR gather ----------------
// aggb[n] = bf16( dinv[n]*(sum_e hWs[src_e] + hWs[n]) + bias )
// 16 lanes per node, 8 channels (ushort8 = 16B) per lane; grid exact (N*16/256)
__global__ __launch_bounds__(256) void gather_kernel(
    const ushort_t* __restrict__ hWs, const int* __restrict__ csr,
    const int* __restrict__ cnt, const float* __restrict__ dinv,
    const float* __restrict__ bias, ushort_t* __restrict__ aggb)
{
  int t = blockIdx.x * 256 + threadIdx.x;
  int n = t >> 4, c8 = (t & 15) * 8;

  ushort8 us = *(const ushort8*)&hWs[n * H + c8];
  float acc[8];
#pragma unroll
  for (int j = 0; j < 8; ++j) acc[j] = bf2f(us[j]);

  int e = n << 6;
  int end = e + min(cnt[n], SLOTS);
  for (; e + 3 < end; e += 4) {
    int s0 = csr[e], s1 = csr[e + 1], s2 = csr[e + 2], s3 = csr[e + 3];
    ushort8 u0 = *(const ushort8*)&hWs[s0 * H + c8];
    ushort8 u1 = *(const ushort8*)&hWs[s1 * H + c8];
    ushort8 u2 = *(const ushort8*)&hWs[s2 * H + c8];
    ushort8 u3 = *(const ushort8*)&hWs[s3 * H + c8];
#pragma unroll
    for (int j = 0; j < 8; ++j)
      acc[j] += (bf2f(u0[j]) + bf2f(u1[j])) + (bf2f(u2[j]) + bf2f(u3[j]));
  }
  for (; e < end; ++e) {
    int s0 = csr[e];
    ushort8 u0 = *(const ushort8*)&hWs[s0 * H + c8];
#pragma unroll
    for (int j = 0; j < 8; ++j) acc[j] += bf2f(u0[j]);
  }

  float dn = dinv[n];
  float4 b0 = *(const float4*)&bias[c8];
  float4 b1 = *(const float4*)&bias[c8 + 4];
  float bb[8] = {b0.x, b0.y, b0.z, b0.w, b1.x, b1.y, b1.z, b1.w};
  ushort8 o;
#pragma unroll
  for (int j = 0; j < 8; ++j) o[j] = f2bf(acc[j] * dn + bb[j]);
  *(ushort8*)&aggb[n * H + c8] = o;
}

// ---------------- batchnorm stats over bf16 agg ----------------
// 391 blocks x 128 rows; block partial reduce -> 256 atomics/block
__global__ __launch_bounds__(256) void bn_stats_kernel(
    const ushort_t* __restrict__ a, float* __restrict__ sums)
{
  __shared__ float red[256];
  int tid = threadIdx.x;
  int c = tid & 127, half = tid >> 7;
  int r0 = blockIdx.x * 128;
  float s = 0.f, q = 0.f;
  for (int i = 0; i < 64; ++i) {
    int r = r0 + i * 2 + half;
    if (r < N) { float v = bf2f(a[r * H + c]); s += v; q += v * v; }
  }
  red[tid] = s; __syncthreads();
  float s2 = (half == 0) ? s + red[tid + 128] : 0.f;
  __syncthreads();
  red[tid] = q; __syncthreads();
  if (half == 0) {
    float q2 = q + red[tid + 128];
    atomAddF(&sums[c], s2);
    atomAddF(&sums[128 + c], q2);
  }
}

// ---------------- global mean pool: chunked run-length accumulate (batch sorted) --------
__global__ __launch_bounds__(256) void pool_kernel(
    const ushort_t* __restrict__ h, const int* __restrict__ batch,
    float* __restrict__ pooled /* pre-zeroed */)
{
  int r0 = blockIdx.x * 128;
  int rend = min(r0 + 128, N);
  int c = threadIdx.x & 127, half = threadIdx.x >> 7;
  float acc = 0.f;
  int curg = -1;
  for (int r = r0 + half; r < rend; r += 2) {
    int g = batch[r];
    if (g != curg) {
      if (curg >= 0) atomAddF(&pooled[curg * H + c], acc);
      acc = 0.f; curg = g;
    }
    acc += bf2f(h[r * H + c]);
  }
  if (curg >= 0) atomAddF(&pooled[curg * H + c], acc);
}

// ---------------- fused head: Linear -> BN -> ReLU -> Linear -> ReLU -> Linear ---------
// single block, 512 threads; z1/z2 live in LDS (64 KB)
__global__ __launch_bounds__(512) void head_kernel(
    const float* __restrict__ pooled, const float* __restrict__ cntg,
    const float* __restrict__ W1, const float* __restrict__ b1,
    const float* __restrict__ hg, const float* __restrict__ hb,
    const float* __restrict__ W2, const float* __restrict__ b2,
    const float* __restrict__ W3, const float* __restrict__ b3,
    float* __restrict__ out)
{
  __shared__ float z1[G * H];   // 32 KB
  __shared__ float z2[G * H];   // 32 KB
  __shared__ float sc[H], sh[H];
  const int t = threadIdx.x;

  // head1: z1 = pooled/cnt @ W1 + b1  (divide folded after dot: pooled holds sums)
#pragma unroll
  for (int i = 0; i < G * H / 512; ++i) {
    int idx = i * 512 + t;
    int g = idx >> 7, c = idx & 127;
    const float* pg = &pooled[g * H];
    float s = 0.f;
#pragma unroll 4
    for (int k = 0; k < H; ++k) s += pg[k] * W1[k * H + c];
    z1[idx] = s / fmaxf(cntg[g], 1.f) + b1[c];
  }
  __syncthreads();

  // BN stats over G per channel
  if (t < H) {
    float s = 0.f, q = 0.f;
    for (int g = 0; g < G; ++g) { float v = z1[g * H + t]; s += v; q += v * v; }
    float mu = s / (float)G;
    float var = q / (float)G - mu * mu;
    float rs = rsqrtf(var + EPS);
    float a = hg[t] * rs;
    sc[t] = a;
    sh[t] = hb[t] - mu * a;
  }
  __syncthreads();

  // apply BN + ReLU in place
#pragma unroll
  for (int i = 0; i < G * H / 512; ++i) {
    int idx = i * 512 + t;
    int c = idx & 127;
    z1[idx] = fmaxf(z1[idx] * sc[c] + sh[c], 0.f);
  }
  __syncthreads();

  // head2: z2 = relu(z1 @ W2 + b2)
#pragma unroll
  for (int i = 0; i < G * H / 512; ++i) {
    int idx = i * 512 + t;
    int g = idx >> 7, c = idx & 127;
    float s = b2[c];
#pragma unroll 4
    for (int k = 0; k < H; ++k) s += z1[g * H + k] * W2[k * H + c];
    z2[idx] = fmaxf(s, 0.f);
  }
  __syncthreads();

  // head3: out = z2 @ W3 + b3
  for (int idx = t; idx < G * OUTC; idx += 512) {
    int g = idx / OUTC, o = idx % OUTC;
    float s = b3[o];
#pragma unroll 4
    for (int k = 0; k < H; ++k) s += z2[g * H + k] * W3[k * OUTC + o];
    out[idx] = s;
  }
}

extern "C" void kernel_launch(void* const* d_in, const int* in_sizes, int n_in,
                              void* d_out, int out_size, void* d_ws, size_t ws_size,
                              hipStream_t stream) {
  const float* x     = (const float*)d_in[0];
  const int*   ei    = (const int*)d_in[1];
  const int*   srcp  = ei;
  const int*   dstp  = ei + E;
  const int*   batch = (const int*)d_in[2];
  const float* convW = (const float*)d_in[3];
  const float* convb = (const float*)d_in[4];
  const float* bng   = (const float*)d_in[5];
  const float* bnb   = (const float*)d_in[6];
  const float* W1    = (const float*)d_in[7];
  const float* b1    = (const float*)d_in[8];
  const float* hg    = (const float*)d_in[9];
  const float* hb    = (const float*)d_in[10];
  const float* W2    = (const float*)d_in[11];
  const float* b2    = (const float*)d_in[12];
  const float* W3    = (const float*)d_in[13];
  const float* b3    = (const float*)d_in[14];
  float* out = (float*)d_out;

  const size_t NH2 = (size_t)N * H / 2;            // bf16 buffer size in float units
  float*    ws     = (float*)d_ws;
  ushort_t* aggb   = (ushort_t*)ws;                // N*H bf16  (16B aligned)
  ushort_t* hWs    = (ushort_t*)(ws + NH2);        // N*H bf16
  ushort_t* WT     = (ushort_t*)(ws + 2 * NH2);    // L*H*H bf16 (49152 floats)
  float*    dinv   = ws + 2 * NH2 + (L * H * H / 2);  // N
  int*      csr    = (int*)(dinv + N);             // N*SLOTS
  int*      cnt    = csr + (size_t)N * SLOTS;      // N   <- zero region start
  float*    bnsums = (float*)(cnt + N);            // (L-1)*256
  float*    pooled = bnsums + (L - 1) * 256;       // G*H <- zero region end
  float*    cntg   = pooled + G * H;               // G

  const int zero_words = N + (L - 1) * 256 + G * H;
  zero_kernel<<<(zero_words + 255) / 256, 256, 0, stream>>>(cnt, zero_words);
  csr_fill_kernel<<<(E + 255) / 256, 256, 0, stream>>>(srcp, dstp, cnt, csr);
  dinv_kernel<<<(N + 255) / 256, 256, 0, stream>>>(cnt, dinv);
  cnt_kernel<<<1, 128, 0, stream>>>(batch, cntg);
  prep_kernel<<<(L * H * H + 255) / 256, 256, 0, stream>>>(convW, WT);

  for (int l = 0; l < L; ++l) {
    const ushort_t* Ab = (l == 0) ? nullptr : aggb;
    const float*    Af = (l == 0) ? x : nullptr;
    const float* bs = (l == 0) ? nullptr : bnsums + (l - 1) * 256;
    const float* ga = (l == 0) ? nullptr : bng + (size_t)(l - 1) * H;
    const float* be = (l == 0) ? nullptr : bnb + (size_t)(l - 1) * H;
    gemm_mfma_kernel<<<(N + 63) / 64, 256, 0, stream>>>(
        Ab, Af, WT + (size_t)l * H * H, dinv, hWs, bs, ga, be);
    gather_kernel<<<N * 16 / 256, 256, 0, stream>>>(
        hWs, csr, cnt, dinv, convb + (size_t)l * H, aggb);
    if (l < L - 1)
      bn_stats_kernel<<<(N + 127) / 128, 256, 0, stream>>>(aggb, bnsums + l * 256);
  }

  pool_kernel<<<(N + 127) / 128, 256, 0, stream>>>(aggb, batch, pooled);
  head_kernel<<<1, 512, 0, stream>>>(pooled, cntg, W1, b1, hg, hb, W2, b2, W3, b3, out);
}

// Round 2
// 655.345 us; speedup vs baseline: 1.1901x; 1.1901x over previous
//
#include <hip/hip_runtime.h>

#define N 50000
#define E 800000
#define H 128
#define G 64
#define OUTC 10
#define L 6
#define EPS 1e-5f
#define SLOTS 64   // fixed bucket capacity; deg ~ Poisson(16), P(deg>64) ~ 2e-18

typedef unsigned short ushort_t;
typedef __attribute__((ext_vector_type(8))) short short8;
typedef __attribute__((ext_vector_type(8))) unsigned short ushort8;
typedef __attribute__((ext_vector_type(4))) float floatx4;

__device__ __forceinline__ void atomAddF(float* p, float v) {
  unsafeAtomicAdd(p, v);   // hw global_atomic_add_f32 on gfx950
}

__device__ __forceinline__ unsigned short f2bf(float f) {
  unsigned u = __float_as_uint(f);
  unsigned r = (u + 0x7FFF + ((u >> 16) & 1)) >> 16;  // RNE
  return (unsigned short)r;
}
__device__ __forceinline__ float bf2f(unsigned short b) {
  return __uint_as_float(((unsigned)b) << 16);
}

// ---------------- init ----------------
__global__ void zero_kernel(int* __restrict__ p, int n) {
  int i = blockIdx.x * blockDim.x + threadIdx.x;
  if (i < n) p[i] = 0;
}

// one-pass bucket CSR build: pos = atomicAdd(cnt[d]); csr[d*64+pos] = src
// replaces deg_count + 3-phase scan + rowptr-indexed fill
__global__ void csr_fill_kernel(const int* __restrict__ src, const int* __restrict__ dst,
                                int* __restrict__ cnt, int* __restrict__ csr) {
  int e = blockIdx.x * blockDim.x + threadIdx.x;
  if (e < E) {
    int d = dst[e];
    int pos = atomicAdd(&cnt[d], 1);
    if (pos < SLOTS) csr[(d << 6) + pos] = src[e];
  }
}

__global__ void dinv_kernel(const int* __restrict__ cnt, float* __restrict__ dinv) {
  int n = blockIdx.x * blockDim.x + threadIdx.x;
  if (n < N) dinv[n] = rsqrtf((float)(cnt[n] + 1));
}

// prep: conv_W -> bf16 transposed WT[l][n][k] (196 KB total)
__global__ void prep_kernel(const float* __restrict__ convW, ushort_t* __restrict__ WT) {
  int j = blockIdx.x * 256 + threadIdx.x;
  if (j < L * H * H) {
    int l = j >> 14, r = j & 16383;   // H*H = 16384
    int n = r >> 7, k = r & 127;
    WT[j] = f2bf(convW[l * 16384 + k * 128 + n]);
  }
}

__global__ void cnt_kernel(const int* __restrict__ batch, float* __restrict__ cntg) {
  __shared__ int lb[G + 1];
  int t = threadIdx.x;  // 128 threads
  if (t <= G) {
    int lo = 0, hi = N;
    while (lo < hi) { int m = (lo + hi) >> 1; if (batch[m] < t) lo = m + 1; else hi = m; }
    lb[t] = lo;
  }
  __syncthreads();
  if (t < G) cntg[t] = (float)(lb[t + 1] - lb[t]);
}

// ---------------- MFMA GEMM: hWs[row] = dinv[row] * (f(A)@W)[row], bf16 ----------------
// A source: Af (f32, layer 0) or Ab (bf16, layers 1..5).
// f = identity (layer 0) or BN+ReLU applied in-register on A fragments.
// LDS-free: A frags from global (L2/L3-resident), B frags from WT (L1-resident).
// block: 256 thr = 4 waves; block tile 64 rows; wave tile 16 rows x 128 cols.
// A layout: A[m=lane&15][k=quad*8+j]; C/D: col=lane&15, row=quad*4+reg.
__global__ __launch_bounds__(256) void gemm_mfma_kernel(
    const ushort_t* __restrict__ Ab, const float* __restrict__ Af,
    const ushort_t* __restrict__ WT,
    const float* __restrict__ dinv, ushort_t* __restrict__ hWs,
    const float* __restrict__ bnsums, const float* __restrict__ gamma,
    const float* __restrict__ beta)
{
  const int tid = threadIdx.x;
  const int wave = tid >> 6, lane = tid & 63;
  const int quad = lane >> 4, m = lane & 15;
  const int row0 = blockIdx.x * 64 + wave * 16;
  const int arow = min(row0 + m, N - 1);
  const float invN = 1.0f / (float)N;

  short8 afrag[4];
  if (Af) {
    // layer 0: read f32 x directly, convert RNE in-register
#pragma unroll
    for (int kc = 0; kc < 4; ++kc) {
      const float* p = &Af[arow * H + kc * 32 + quad * 8];
      float4 f0 = *(const float4*)p;
      float4 f1 = *(const float4*)(p + 4);
      short8 a;
      a[0] = (short)f2bf(f0.x); a[1] = (short)f2bf(f0.y);
      a[2] = (short)f2bf(f0.z); a[3] = (short)f2bf(f0.w);
      a[4] = (short)f2bf(f1.x); a[5] = (short)f2bf(f1.y);
      a[6] = (short)f2bf(f1.z); a[7] = (short)f2bf(f1.w);
      afrag[kc] = a;
    }
  } else {
#pragma unroll
    for (int kc = 0; kc < 4; ++kc) {
      ushort8 raw = *(const ushort8*)&Ab[arow * H + kc * 32 + quad * 8];
      if (bnsums) {
        const int k0 = kc * 32 + quad * 8;
#pragma unroll
        for (int j = 0; j < 8; ++j) {
          float s = bnsums[k0 + j], q = bnsums[128 + k0 + j];
          float mu = s * invN;
          float var = q * invN - mu * mu;
          float rs = rsqrtf(var + EPS);
          float sc = gamma[k0 + j] * rs;
          float sh = beta[k0 + j] - mu * sc;
          raw[j] = f2bf(fmaxf(bf2f(raw[j]) * sc + sh, 0.f));
        }
      }
      short8 a;
#pragma unroll
      for (int j = 0; j < 8; ++j) a[j] = (short)raw[j];
      afrag[kc] = a;
    }
  }

  float dv[4];
#pragma unroll
  for (int i = 0; i < 4; ++i) {
    int r = row0 + quad * 4 + i;
    dv[i] = (r < N) ? dinv[r] : 0.f;
  }

  const short* WTs = (const short*)WT;
#pragma unroll
  for (int nt = 0; nt < 8; ++nt) {
    floatx4 acc = {0.f, 0.f, 0.f, 0.f};
#pragma unroll
    for (int kc = 0; kc < 4; ++kc) {
      short8 bfrag = *(const short8*)&WTs[(nt * 16 + m) * H + kc * 32 + quad * 8];
      acc = __builtin_amdgcn_mfma_f32_16x16x32_bf16(afrag[kc], bfrag, acc, 0, 0, 0);
    }
    int col = nt * 16 + m;
#pragma unroll
    for (int i = 0; i < 4; ++i) {
      int r = row0 + quad * 4 + i;
      if (r < N) hWs[r * H + col] = f2bf(acc[i] * dv[i]);
    }
  }
}

// ---------------- CSR gather ----------------
// aggb[n] = bf16( dinv[n]*(sum_e hWs[src_e] + hWs[n]) + bias )
// 16 lanes per node, 8 channels (ushort8 = 16B) per lane; grid exact (N*16/256)
__global__ __launch_bounds__(256) void gather_kernel(
    const ushort_t* __restrict__ hWs, const int* __restrict__ csr,
    const int* __restrict__ cnt, const float* __restrict__ dinv,
    const float* __restrict__ bias, ushort_t* __restrict__ aggb)
{
  int t = blockIdx.x * 256 + threadIdx.x;
  int n = t >> 4, c8 = (t & 15) * 8;

  ushort8 us = *(const ushort8*)&hWs[n * H + c8];
  float acc[8];
#pragma unroll
  for (int j = 0; j < 8; ++j) acc[j] = bf2f(us[j]);

  int e = n << 6;
  int end = e + min(cnt[n], SLOTS);
  for (; e + 3 < end; e += 4) {
    int s0 = csr[e], s1 = csr[e + 1], s2 = csr[e + 2], s3 = csr[e + 3];
    ushort8 u0 = *(const ushort8*)&hWs[s0 * H + c8];
    ushort8 u1 = *(const ushort8*)&hWs[s1 * H + c8];
    ushort8 u2 = *(const ushort8*)&hWs[s2 * H + c8];
    ushort8 u3 = *(const ushort8*)&hWs[s3 * H + c8];
#pragma unroll
    for (int j = 0; j < 8; ++j)
      acc[j] += (bf2f(u0[j]) + bf2f(u1[j])) + (bf2f(u2[j]) + bf2f(u3[j]));
  }
  for (; e < end; ++e) {
    int s0 = csr[e];
    ushort8 u0 = *(const ushort8*)&hWs[s0 * H + c8];
#pragma unroll
    for (int j = 0; j < 8; ++j) acc[j] += bf2f(u0[j]);
  }

  float dn = dinv[n];
  float4 b0 = *(const float4*)&bias[c8];
  float4 b1 = *(const float4*)&bias[c8 + 4];
  float bb[8] = {b0.x, b0.y, b0.z, b0.w, b1.x, b1.y, b1.z, b1.w};
  ushort8 o;
#pragma unroll
  for (int j = 0; j < 8; ++j) o[j] = f2bf(acc[j] * dn + bb[j]);
  *(ushort8*)&aggb[n * H + c8] = o;
}

// ---------------- batchnorm stats over bf16 agg ----------------
// 391 blocks x 128 rows; block partial reduce -> 256 atomics/block
__global__ __launch_bounds__(256) void bn_stats_kernel(
    const ushort_t* __restrict__ a, float* __restrict__ sums)
{
  __shared__ float red[256];
  int tid = threadIdx.x;
  int c = tid & 127, half = tid >> 7;
  int r0 = blockIdx.x * 128;
  float s = 0.f, q = 0.f;
  for (int i = 0; i < 64; ++i) {
    int r = r0 + i * 2 + half;
    if (r < N) { float v = bf2f(a[r * H + c]); s += v; q += v * v; }
  }
  red[tid] = s; __syncthreads();
  float s2 = (half == 0) ? s + red[tid + 128] : 0.f;
  __syncthreads();
  red[tid] = q; __syncthreads();
  if (half == 0) {
    float q2 = q + red[tid + 128];
    atomAddF(&sums[c], s2);
    atomAddF(&sums[128 + c], q2);
  }
}

// ---------------- global mean pool: chunked run-length accumulate (batch sorted) --------
__global__ __launch_bounds__(256) void pool_kernel(
    const ushort_t* __restrict__ h, const int* __restrict__ batch,
    float* __restrict__ pooled /* pre-zeroed */)
{
  int r0 = blockIdx.x * 128;
  int rend = min(r0 + 128, N);
  int c = threadIdx.x & 127, half = threadIdx.x >> 7;
  float acc = 0.f;
  int curg = -1;
  for (int r = r0 + half; r < rend; r += 2) {
    int g = batch[r];
    if (g != curg) {
      if (curg >= 0) atomAddF(&pooled[curg * H + c], acc);
      acc = 0.f; curg = g;
    }
    acc += bf2f(h[r * H + c]);
  }
  if (curg >= 0) atomAddF(&pooled[curg * H + c], acc);
}

// ---------------- head (split, multi-block: latency-hiding via 32-64 blocks) ----------
__global__ void head1_kernel(const float* __restrict__ pooled, const float* __restrict__ cntg,
                             const float* __restrict__ W1, const float* __restrict__ b1,
                             float* __restrict__ z1)
{
  int t = blockIdx.x * 256 + threadIdx.x;  // 8192
  int g = t >> 7, c = t & 127;
  float s = 0.f;
  for (int k = 0; k < H; ++k) s += pooled[g * H + k] * W1[k * H + c];
  z1[t] = s / fmaxf(cntg[g], 1.0f) + b1[c];
}

__global__ void head_bn_kernel(float* __restrict__ z1,
                               const float* __restrict__ gamma, const float* __restrict__ beta)
{
  int c = threadIdx.x;  // 128 threads
  float s = 0.f, q = 0.f;
  for (int g = 0; g < G; ++g) { float v = z1[g * H + c]; s += v; q += v * v; }
  float mu = s / (float)G;
  float var = q / (float)G - mu * mu;
  float rs = rsqrtf(var + EPS);
  float ga = gamma[c], be = beta[c];
  for (int g = 0; g < G; ++g) {
    float v = z1[g * H + c];
    z1[g * H + c] = fmaxf((v - mu) * rs * ga + be, 0.f);
  }
}

__global__ void head2_kernel(const float* __restrict__ z1, const float* __restrict__ W2,
                             const float* __restrict__ b2, float* __restrict__ z2)
{
  int t = blockIdx.x * 256 + threadIdx.x;  // 8192
  int g = t >> 7, c = t & 127;
  float s = b2[c];
  for (int k = 0; k < H; ++k) s += z1[g * H + k] * W2[k * H + c];
  z2[t] = fmaxf(s, 0.f);
}

__global__ void head3_kernel(const float* __restrict__ z2, const float* __restrict__ W3,
                             const float* __restrict__ b3, float* __restrict__ out)
{
  int t = blockIdx.x * 256 + threadIdx.x;
  if (t < G * OUTC) {
    int g = t / OUTC, o = t % OUTC;
    float s = b3[o];
    for (int k = 0; k < H; ++k) s += z2[g * H + k] * W3[k * OUTC + o];
    out[t] = s;
  }
}

extern "C" void kernel_launch(void* const* d_in, const int* in_sizes, int n_in,
                              void* d_out, int out_size, void* d_ws, size_t ws_size,
                              hipStream_t stream) {
  const float* x     = (const float*)d_in[0];
  const int*   ei    = (const int*)d_in[1];
  const int*   srcp  = ei;
  const int*   dstp  = ei + E;
  const int*   batch = (const int*)d_in[2];
  const float* convW = (const float*)d_in[3];
  const float* convb = (const float*)d_in[4];
  const float* bng   = (const float*)d_in[5];
  const float* bnb   = (const float*)d_in[6];
  const float* W1    = (const float*)d_in[7];
  const float* b1    = (const float*)d_in[8];
  const float* hg    = (const float*)d_in[9];
  const float* hb    = (const float*)d_in[10];
  const float* W2    = (const float*)d_in[11];
  const float* b2    = (const float*)d_in[12];
  const float* W3    = (const float*)d_in[13];
  const float* b3    = (const float*)d_in[14];
  float* out = (float*)d_out;

  const size_t NH2 = (size_t)N * H / 2;            // bf16 buffer size in float units
  float*    ws     = (float*)d_ws;
  ushort_t* aggb   = (ushort_t*)ws;                // N*H bf16  (16B aligned)
  ushort_t* hWs    = (ushort_t*)(ws + NH2);        // N*H bf16
  ushort_t* WT     = (ushort_t*)(ws + 2 * NH2);    // L*H*H bf16 (49152 floats)
  float*    dinv   = ws + 2 * NH2 + (L * H * H / 2);  // N
  int*      csr    = (int*)(dinv + N);             // N*SLOTS
  int*      cnt    = csr + (size_t)N * SLOTS;      // N   <- zero region start
  float*    bnsums = (float*)(cnt + N);            // (L-1)*256
  float*    pooled = bnsums + (L - 1) * 256;       // G*H <- zero region end
  float*    cntg   = pooled + G * H;               // G
  float*    z1     = cntg + G;                     // G*H
  float*    z2     = z1 + G * H;                   // G*H

  const int zero_words = N + (L - 1) * 256 + G * H;
  zero_kernel<<<(zero_words + 255) / 256, 256, 0, stream>>>(cnt, zero_words);
  csr_fill_kernel<<<(E + 255) / 256, 256, 0, stream>>>(srcp, dstp, cnt, csr);
  dinv_kernel<<<(N + 255) / 256, 256, 0, stream>>>(cnt, dinv);
  cnt_kernel<<<1, 128, 0, stream>>>(batch, cntg);
  prep_kernel<<<(L * H * H + 255) / 256, 256, 0, stream>>>(convW, WT);

  for (int l = 0; l < L; ++l) {
    const ushort_t* Ab = (l == 0) ? nullptr : aggb;
    const float*    Af = (l == 0) ? x : nullptr;
    const float* bs = (l == 0) ? nullptr : bnsums + (l - 1) * 256;
    const float* ga = (l == 0) ? nullptr : bng + (size_t)(l - 1) * H;
    const float* be = (l == 0) ? nullptr : bnb + (size_t)(l - 1) * H;
    gemm_mfma_kernel<<<(N + 63) / 64, 256, 0, stream>>>(
        Ab, Af, WT + (size_t)l * H * H, dinv, hWs, bs, ga, be);
    gather_kernel<<<N * 16 / 256, 256, 0, stream>>>(
        hWs, csr, cnt, dinv, convb + (size_t)l * H, aggb);
    if (l < L - 1)
      bn_stats_kernel<<<(N + 127) / 128, 256, 0, stream>>>(aggb, bnsums + l * 256);
  }

  pool_kernel<<<(N + 127) / 128, 256, 0, stream>>>(aggb, batch, pooled);
  head1_kernel<<<32, 256, 0, stream>>>(pooled, cntg, W1, b1, z1);
  head_bn_kernel<<<1, 128, 0, stream>>>(z1, hg, hb);
  head2_kernel<<<32, 256, 0, stream>>>(z1, W2, b2, z2);
  head3_kernel<<<3, 256, 0, stream>>>(z2, W3, b3, out);
}

// Round 3
// 618.212 us; speedup vs baseline: 1.2616x; 1.0601x over previous
//
#include <hip/hip_runtime.h>

#define N 50000
#define E 800000
#define H 128
#define G 64
#define OUTC 10
#define L 6
#define EPS 1e-5f
#define SLOTS 64   // fixed bucket capacity; deg ~ Poisson(16), P(deg>64) ~ 2e-18

typedef unsigned short ushort_t;
typedef __attribute__((ext_vector_type(8))) short short8;
typedef __attribute__((ext_vector_type(8))) unsigned short ushort8;
typedef __attribute__((ext_vector_type(4))) float floatx4;

__device__ __forceinline__ void atomAddF(float* p, float v) {
  unsafeAtomicAdd(p, v);   // hw global_atomic_add_f32 on gfx950
}

__device__ __forceinline__ unsigned short f2bf(float f) {
  unsigned u = __float_as_uint(f);
  unsigned r = (u + 0x7FFF + ((u >> 16) & 1)) >> 16;  // RNE
  return (unsigned short)r;
}
__device__ __forceinline__ float bf2f(unsigned short b) {
  return __uint_as_float(((unsigned)b) << 16);
}

// ---------------- init ----------------
__global__ void zero_kernel(int* __restrict__ p, int n) {
  int i = blockIdx.x * blockDim.x + threadIdx.x;
  if (i < n) p[i] = 0;
}

// one-pass bucket CSR build (ushort entries: N=50000 < 65536)
// bucket = 128 B -> 64B line holds 32 entries: halves cross-XCD line bounce
__global__ void csr_fill_kernel(const int* __restrict__ src, const int* __restrict__ dst,
                                int* __restrict__ cnt, ushort_t* __restrict__ csru) {
  int e = blockIdx.x * blockDim.x + threadIdx.x;
  if (e < E) {
    int d = dst[e];
    int pos = atomicAdd(&cnt[d], 1);
    if (pos < SLOTS) csru[(d << 6) + pos] = (ushort_t)src[e];
  }
}

__global__ void dinv_kernel(const int* __restrict__ cnt, float* __restrict__ dinv) {
  int n = blockIdx.x * blockDim.x + threadIdx.x;
  if (n < N) dinv[n] = rsqrtf((float)(cnt[n] + 1));
}

// prep: conv_W -> bf16 transposed WT[l][n][k] (196 KB total)
__global__ void prep_kernel(const float* __restrict__ convW, ushort_t* __restrict__ WT) {
  int j = blockIdx.x * 256 + threadIdx.x;
  if (j < L * H * H) {
    int l = j >> 14, r = j & 16383;   // H*H = 16384
    int n = r >> 7, k = r & 127;
    WT[j] = f2bf(convW[l * 16384 + k * 128 + n]);
  }
}

__global__ void cnt_kernel(const int* __restrict__ batch, float* __restrict__ cntg) {
  __shared__ int lb[G + 1];
  int t = threadIdx.x;  // 128 threads
  if (t <= G) {
    int lo = 0, hi = N;
    while (lo < hi) { int m = (lo + hi) >> 1; if (batch[m] < t) lo = m + 1; else hi = m; }
    lb[t] = lo;
  }
  __syncthreads();
  if (t < G) cntg[t] = (float)(lb[t + 1] - lb[t]);
}

// ---------------- MFMA GEMM: hWs[row] = dinv[row] * (f(A)@W)[row], bf16 ----------------
// A source: Af (f32, layer 0) or Ab (bf16, layers 1..5).
// f = identity (layer 0) or BN+ReLU applied in-register on A fragments.
// LDS-free: A frags from global (L2/L3-resident), B frags from WT (L1-resident).
// block: 256 thr = 4 waves; block tile 64 rows; wave tile 16 rows x 128 cols.
// A layout: A[m=lane&15][k=quad*8+j]; C/D: col=lane&15, row=quad*4+reg.
__global__ __launch_bounds__(256) void gemm_mfma_kernel(
    const ushort_t* __restrict__ Ab, const float* __restrict__ Af,
    const ushort_t* __restrict__ WT,
    const float* __restrict__ dinv, ushort_t* __restrict__ hWs,
    const float* __restrict__ bnsums, const float* __restrict__ gamma,
    const float* __restrict__ beta)
{
  const int tid = threadIdx.x;
  const int wave = tid >> 6, lane = tid & 63;
  const int quad = lane >> 4, m = lane & 15;
  const int row0 = blockIdx.x * 64 + wave * 16;
  const int arow = min(row0 + m, N - 1);
  const float invN = 1.0f / (float)N;

  short8 afrag[4];
  if (Af) {
    // layer 0: read f32 x directly, convert RNE in-register
#pragma unroll
    for (int kc = 0; kc < 4; ++kc) {
      const float* p = &Af[arow * H + kc * 32 + quad * 8];
      float4 f0 = *(const float4*)p;
      float4 f1 = *(const float4*)(p + 4);
      short8 a;
      a[0] = (short)f2bf(f0.x); a[1] = (short)f2bf(f0.y);
      a[2] = (short)f2bf(f0.z); a[3] = (short)f2bf(f0.w);
      a[4] = (short)f2bf(f1.x); a[5] = (short)f2bf(f1.y);
      a[6] = (short)f2bf(f1.z); a[7] = (short)f2bf(f1.w);
      afrag[kc] = a;
    }
  } else {
#pragma unroll
    for (int kc = 0; kc < 4; ++kc) {
      ushort8 raw = *(const ushort8*)&Ab[arow * H + kc * 32 + quad * 8];
      if (bnsums) {
        const int k0 = kc * 32 + quad * 8;
#pragma unroll
        for (int j = 0; j < 8; ++j) {
          float s = bnsums[k0 + j], q = bnsums[128 + k0 + j];
          float mu = s * invN;
          float var = q * invN - mu * mu;
          float rs = rsqrtf(var + EPS);
          float sc = gamma[k0 + j] * rs;
          float sh = beta[k0 + j] - mu * sc;
          raw[j] = f2bf(fmaxf(bf2f(raw[j]) * sc + sh, 0.f));
        }
      }
      short8 a;
#pragma unroll
      for (int j = 0; j < 8; ++j) a[j] = (short)raw[j];
      afrag[kc] = a;
    }
  }

  float dv[4];
#pragma unroll
  for (int i = 0; i < 4; ++i) {
    int r = row0 + quad * 4 + i;
    dv[i] = (r < N) ? dinv[r] : 0.f;
  }

  const short* WTs = (const short*)WT;
#pragma unroll
  for (int nt = 0; nt < 8; ++nt) {
    floatx4 acc = {0.f, 0.f, 0.f, 0.f};
#pragma unroll
    for (int kc = 0; kc < 4; ++kc) {
      short8 bfrag = *(const short8*)&WTs[(nt * 16 + m) * H + kc * 32 + quad * 8];
      acc = __builtin_amdgcn_mfma_f32_16x16x32_bf16(afrag[kc], bfrag, acc, 0, 0, 0);
    }
    int col = nt * 16 + m;
#pragma unroll
    for (int i = 0; i < 4; ++i) {
      int r = row0 + quad * 4 + i;
      if (r < N) hWs[r * H + col] = f2bf(acc[i] * dv[i]);
    }
  }
}

// ---------------- CSR gather ----------------
// aggb[n] = bf16( dinv[n]*(sum_e hWs[src_e] + hWs[n]) + bias )
// 16 lanes per node, 8 channels (ushort8 = 16B) per lane; grid exact (N*16/256)
// 8-deep unrolled neighbor loop: 8 outstanding row loads (latency hiding)
__global__ __launch_bounds__(256) void gather_kernel(
    const ushort_t* __restrict__ hWs, const ushort_t* __restrict__ csru,
    const int* __restrict__ cnt, const float* __restrict__ dinv,
    const float* __restrict__ bias, ushort_t* __restrict__ aggb)
{
  int t = blockIdx.x * 256 + threadIdx.x;
  int n = t >> 4, c8 = (t & 15) * 8;

  ushort8 us = *(const ushort8*)&hWs[n * H + c8];
  float acc[8];
#pragma unroll
  for (int j = 0; j < 8; ++j) acc[j] = bf2f(us[j]);

  const int base = n << 6;
  const int deg = min(cnt[n], SLOTS);
  int e = 0;
  for (; e + 8 <= deg; e += 8) {
    ushort8 idx = *(const ushort8*)&csru[base + e];   // 16B aligned (base%64==0, e%8==0)
    ushort8 u0 = *(const ushort8*)&hWs[(int)idx[0] * H + c8];
    ushort8 u1 = *(const ushort8*)&hWs[(int)idx[1] * H + c8];
    ushort8 u2 = *(const ushort8*)&hWs[(int)idx[2] * H + c8];
    ushort8 u3 = *(const ushort8*)&hWs[(int)idx[3] * H + c8];
    ushort8 u4 = *(const ushort8*)&hWs[(int)idx[4] * H + c8];
    ushort8 u5 = *(const ushort8*)&hWs[(int)idx[5] * H + c8];
    ushort8 u6 = *(const ushort8*)&hWs[(int)idx[6] * H + c8];
    ushort8 u7 = *(const ushort8*)&hWs[(int)idx[7] * H + c8];
#pragma unroll
    for (int j = 0; j < 8; ++j)
      acc[j] += ((bf2f(u0[j]) + bf2f(u1[j])) + (bf2f(u2[j]) + bf2f(u3[j]))) +
                ((bf2f(u4[j]) + bf2f(u5[j])) + (bf2f(u6[j]) + bf2f(u7[j])));
  }
  for (; e < deg; ++e) {
    int s0 = csru[base + e];
    ushort8 u0 = *(const ushort8*)&hWs[s0 * H + c8];
#pragma unroll
    for (int j = 0; j < 8; ++j) acc[j] += bf2f(u0[j]);
  }

  float dn = dinv[n];
  float4 b0 = *(const float4*)&bias[c8];
  float4 b1 = *(const float4*)&bias[c8 + 4];
  float bb[8] = {b0.x, b0.y, b0.z, b0.w, b1.x, b1.y, b1.z, b1.w};
  ushort8 o;
#pragma unroll
  for (int j = 0; j < 8; ++j) o[j] = f2bf(acc[j] * dn + bb[j]);
  *(ushort8*)&aggb[n * H + c8] = o;
}

// ---------------- batchnorm stats over bf16 agg (vectorized ushort8 loads) ----------
// 391 blocks x 128 rows; thread: cg=tid&15 (8 channels), nn=tid>>4 (row in 16-group)
// reduce: shfl over nn-in-wave (x16, x32) -> LDS across 4 waves -> 256 atomics/block
__global__ __launch_bounds__(256) void bn_stats_kernel(
    const ushort_t* __restrict__ a, float* __restrict__ sums)
{
  __shared__ float redS[4 * 128], redQ[4 * 128];
  int tid = threadIdx.x;
  int cg = tid & 15, nn = tid >> 4;
  int c8 = cg * 8;
  int r0 = blockIdx.x * 128;
  float s[8], q[8];
#pragma unroll
  for (int j = 0; j < 8; ++j) { s[j] = 0.f; q[j] = 0.f; }
#pragma unroll
  for (int i = 0; i < 8; ++i) {
    int r = r0 + i * 16 + nn;
    if (r < N) {
      ushort8 u = *(const ushort8*)&a[r * H + c8];
#pragma unroll
      for (int j = 0; j < 8; ++j) { float v = bf2f(u[j]); s[j] += v; q[j] += v * v; }
    }
  }
  int wave = tid >> 6, lane = tid & 63;
#pragma unroll
  for (int j = 0; j < 8; ++j) {
    s[j] += __shfl_xor(s[j], 16); s[j] += __shfl_xor(s[j], 32);
    q[j] += __shfl_xor(q[j], 16); q[j] += __shfl_xor(q[j], 32);
  }
  if (lane < 16) {
#pragma unroll
    for (int j = 0; j < 8; ++j) {
      redS[wave * 128 + lane * 8 + j] = s[j];
      redQ[wave * 128 + lane * 8 + j] = q[j];
    }
  }
  __syncthreads();
  if (tid < 128) {
    float v = redS[tid] + redS[128 + tid] + redS[256 + tid] + redS[384 + tid];
    atomAddF(&sums[tid], v);
  } else {
    int t2 = tid - 128;
    float v = redQ[t2] + redQ[128 + t2] + redQ[256 + t2] + redQ[384 + t2];
    atomAddF(&sums[128 + t2], v);
  }
}

// ---------------- global mean pool: chunked run-length accumulate (batch sorted) --------
__global__ __launch_bounds__(256) void pool_kernel(
    const ushort_t* __restrict__ h, const int* __restrict__ batch,
    float* __restrict__ pooled /* pre-zeroed */)
{
  int r0 = blockIdx.x * 128;
  int rend = min(r0 + 128, N);
  int c = threadIdx.x & 127, half = threadIdx.x >> 7;
  float acc = 0.f;
  int curg = -1;
  for (int r = r0 + half; r < rend; r += 2) {
    int g = batch[r];
    if (g != curg) {
      if (curg >= 0) atomAddF(&pooled[curg * H + c], acc);
      acc = 0.f; curg = g;
    }
    acc += bf2f(h[r * H + c]);
  }
  if (curg >= 0) atomAddF(&pooled[curg * H + c], acc);
}

// ---------------- head (split, multi-block: latency-hiding via 32-64 blocks) ----------
__global__ void head1_kernel(const float* __restrict__ pooled, const float* __restrict__ cntg,
                             const float* __restrict__ W1, const float* __restrict__ b1,
                             float* __restrict__ z1)
{
  int t = blockIdx.x * 256 + threadIdx.x;  // 8192
  int g = t >> 7, c = t & 127;
  float s = 0.f;
  for (int k = 0; k < H; ++k) s += pooled[g * H + k] * W1[k * H + c];
  z1[t] = s / fmaxf(cntg[g], 1.0f) + b1[c];
}

__global__ void head_bn_kernel(float* __restrict__ z1,
                               const float* __restrict__ gamma, const float* __restrict__ beta)
{
  int c = threadIdx.x;  // 128 threads
  float s = 0.f, q = 0.f;
  for (int g = 0; g < G; ++g) { float v = z1[g * H + c]; s += v; q += v * v; }
  float mu = s / (float)G;
  float var = q / (float)G - mu * mu;
  float rs = rsqrtf(var + EPS);
  float ga = gamma[c], be = beta[c];
  for (int g = 0; g < G; ++g) {
    float v = z1[g * H + c];
    z1[g * H + c] = fmaxf((v - mu) * rs * ga + be, 0.f);
  }
}

__global__ void head2_kernel(const float* __restrict__ z1, const float* __restrict__ W2,
                             const float* __restrict__ b2, float* __restrict__ z2)
{
  int t = blockIdx.x * 256 + threadIdx.x;  // 8192
  int g = t >> 7, c = t & 127;
  float s = b2[c];
  for (int k = 0; k < H; ++k) s += z1[g * H + k] * W2[k * H + c];
  z2[t] = fmaxf(s, 0.f);
}

__global__ void head3_kernel(const float* __restrict__ z2, const float* __restrict__ W3,
                             const float* __restrict__ b3, float* __restrict__ out)
{
  int t = blockIdx.x * 256 + threadIdx.x;
  if (t < G * OUTC) {
    int g = t / OUTC, o = t % OUTC;
    float s = b3[o];
    for (int k = 0; k < H; ++k) s += z2[g * H + k] * W3[k * OUTC + o];
    out[t] = s;
  }
}

extern "C" void kernel_launch(void* const* d_in, const int* in_sizes, int n_in,
                              void* d_out, int out_size, void* d_ws, size_t ws_size,
                              hipStream_t stream) {
  const float* x     = (const float*)d_in[0];
  const int*   ei    = (const int*)d_in[1];
  const int*   srcp  = ei;
  const int*   dstp  = ei + E;
  const int*   batch = (const int*)d_in[2];
  const float* convW = (const float*)d_in[3];
  const float* convb = (const float*)d_in[4];
  const float* bng   = (const float*)d_in[5];
  const float* bnb   = (const float*)d_in[6];
  const float* W1    = (const float*)d_in[7];
  const float* b1    = (const float*)d_in[8];
  const float* hg    = (const float*)d_in[9];
  const float* hb    = (const float*)d_in[10];
  const float* W2    = (const float*)d_in[11];
  const float* b2    = (const float*)d_in[12];
  const float* W3    = (const float*)d_in[13];
  const float* b3    = (const float*)d_in[14];
  float* out = (float*)d_out;

  const size_t NH2 = (size_t)N * H / 2;            // bf16 buffer size in float units
  float*    ws     = (float*)d_ws;
  ushort_t* aggb   = (ushort_t*)ws;                // N*H bf16  (16B aligned)
  ushort_t* hWs    = (ushort_t*)(ws + NH2);        // N*H bf16
  ushort_t* WT     = (ushort_t*)(ws + 2 * NH2);    // L*H*H bf16 (49152 floats)
  float*    dinv   = ws + 2 * NH2 + (L * H * H / 2);  // N
  ushort_t* csru   = (ushort_t*)(dinv + N);        // N*SLOTS ushort (6.4 MB)
  int*      cnt    = (int*)(csru + (size_t)N * SLOTS); // N   <- zero region start
  float*    bnsums = (float*)(cnt + N);            // (L-1)*256
  float*    pooled = bnsums + (L - 1) * 256;       // G*H <- zero region end
  float*    cntg   = pooled + G * H;               // G
  float*    z1     = cntg + G;                     // G*H
  float*    z2     = z1 + G * H;                   // G*H

  const int zero_words = N + (L - 1) * 256 + G * H;
  zero_kernel<<<(zero_words + 255) / 256, 256, 0, stream>>>(cnt, zero_words);
  csr_fill_kernel<<<(E + 255) / 256, 256, 0, stream>>>(srcp, dstp, cnt, csru);
  dinv_kernel<<<(N + 255) / 256, 256, 0, stream>>>(cnt, dinv);
  cnt_kernel<<<1, 128, 0, stream>>>(batch, cntg);
  prep_kernel<<<(L * H * H + 255) / 256, 256, 0, stream>>>(convW, WT);

  for (int l = 0; l < L; ++l) {
    const ushort_t* Ab = (l == 0) ? nullptr : aggb;
    const float*    Af = (l == 0) ? x : nullptr;
    const float* bs = (l == 0) ? nullptr : bnsums + (l - 1) * 256;
    const float* ga = (l == 0) ? nullptr : bng + (size_t)(l - 1) * H;
    const float* be = (l == 0) ? nullptr : bnb + (size_t)(l - 1) * H;
    gemm_mfma_kernel<<<(N + 63) / 64, 256, 0, stream>>>(
        Ab, Af, WT + (size_t)l * H * H, dinv, hWs, bs, ga, be);
    gather_kernel<<<N * 16 / 256, 256, 0, stream>>>(
        hWs, csru, cnt, dinv, convb + (size_t)l * H, aggb);
    if (l < L - 1)
      bn_stats_kernel<<<(N + 127) / 128, 256, 0, stream>>>(aggb, bnsums + l * 256);
  }

  pool_kernel<<<(N + 127) / 128, 256, 0, stream>>>(aggb, batch, pooled);
  head1_kernel<<<32, 256, 0, stream>>>(pooled, cntg, W1, b1, z1);
  head_bn_kernel<<<1, 128, 0, stream>>>(z1, hg, hb);
  head2_kernel<<<32, 256, 0, stream>>>(z1, W2, b2, z2);
  head3_kernel<<<3, 256, 0, stream>>>(z2, W3, b3, out);
}